// Round 3
// baseline (705.509 us; speedup 1.0000x reference)
//
#include <hip/hip_runtime.h>
#include <cstdint>
#include <cstddef>

#define MR 2048
#define NC 4096
#define M3 683
#define SEG 64        // segments for 2048-row cumsums
#define HSEG 32       // MR/SEG
#define SEGD 22       // segments for 683-row cumsum
#define H3D 32        // rows per decay segment (ceil(683/22)=32)
#define VT 64         // vertical box tile height
#define VTILES 32     // MR/VT
#define PSEG 64       // 32-row segments for final cumsum
#define NORM (1.0f/9604.0f)
// skewed LDS index: +1 float pad per 16 → stride-17 between threads
#define SK(k) ((k)+((k)>>4))

union F4u { float4 v; float f[4]; };
union F2u { float2 v; float f[2]; };

__device__ __forceinline__ float sp(float v){
  // jax.nn.softplus = max(x,0) + log1p(exp(-|x|))
  return fmaxf(v, 0.0f) + log1pf(expf(-fabsf(v)));
}

// ---- segmented column scans pass 1 (fused decay+b), float4 columns ----

__global__ void seg_sum_both(const float* __restrict__ bneg, const float* __restrict__ dcol,
                             const float* __restrict__ b, const float* __restrict__ w,
                             float* __restrict__ TD, float* __restrict__ Pd,
                             float* __restrict__ TB, float* __restrict__ Pb){
  int s = blockIdx.x;
  size_t col = ((size_t)blockIdx.y*blockDim.x + threadIdx.x)*4;
  if(s < SEGD){
    int i0 = s*H3D, i1 = min(M3, i0+H3D);
    float acc[4]={0.f,0.f,0.f,0.f};
    int i = i0;
    for(; i+8<=i1; i+=8){
      F4u bv[8], dv[8];
      #pragma unroll
      for(int t=0;t<8;t++){ size_t o=(size_t)(i+t)*NC+col;
        bv[t].v=*(const float4*)(bneg+o); dv[t].v=*(const float4*)(dcol+o); }
      #pragma unroll
      for(int t=0;t<8;t++){
        F4u x; size_t o=(size_t)(i+t)*NC+col;
        #pragma unroll
        for(int k=0;k<4;k++){ x.f[k]=bv[t].f[k]*sp(dv[t].f[k]); acc[k]+=x.f[k]; }
        *(float4*)(TD+o)=x.v;
      }
    }
    for(; i<i1; i++){
      F4u bv,dv,x; size_t o=(size_t)i*NC+col;
      bv.v=*(const float4*)(bneg+o); dv.v=*(const float4*)(dcol+o);
      #pragma unroll
      for(int k=0;k<4;k++){ x.f[k]=bv.f[k]*sp(dv.f[k]); acc[k]+=x.f[k]; }
      *(float4*)(TD+o)=x.v;
    }
    F4u a; a.f[0]=acc[0];a.f[1]=acc[1];a.f[2]=acc[2];a.f[3]=acc[3];
    *(float4*)(Pd+(size_t)s*NC+col)=a.v;
  } else {
    int sb = s - SEGD;
    int i0 = sb*HSEG;
    float acc[4]={0.f,0.f,0.f,0.f};
    for(int g=0;g<HSEG;g+=8){
      F4u bv[8], wv[8];
      #pragma unroll
      for(int t=0;t<8;t++){ size_t o=(size_t)(i0+g+t)*NC+col;
        bv[t].v=*(const float4*)(b+o); wv[t].v=*(const float4*)(w+o); }
      #pragma unroll
      for(int t=0;t<8;t++){
        F4u x; size_t o=(size_t)(i0+g+t)*NC+col;
        #pragma unroll
        for(int k=0;k<4;k++){ x.f[k]=bv[t].f[k]*sp(wv[t].f[k]); acc[k]+=x.f[k]; }
        *(float4*)(TB+o)=x.v;
      }
    }
    F4u a; a.f[0]=acc[0];a.f[1]=acc[1];a.f[2]=acc[2];a.f[3]=acc[3];
    *(float4*)(Pb+(size_t)sb*NC+col)=a.v;
  }
}

// ---- pass 2: exclusive scans of both partial arrays in one launch ----

__global__ void scan_excl_both(float* __restrict__ Pd, float* __restrict__ Pb){
  int j = blockIdx.x*blockDim.x + threadIdx.x;
  {
    float run=0.f; int s=0;
    for(; s+8<=SEGD; s+=8){
      float v[8];
      #pragma unroll
      for(int t=0;t<8;t++) v[t]=Pd[(s+t)*NC+j];
      #pragma unroll
      for(int t=0;t<8;t++){ Pd[(s+t)*NC+j]=run; run+=v[t]; }
    }
    for(; s<SEGD; s++){ float t=Pd[s*NC+j]; Pd[s*NC+j]=run; run+=t; }
  }
  {
    float run=0.f;
    for(int s=0; s<SEG; s+=8){
      float v[8];
      #pragma unroll
      for(int t=0;t<8;t++) v[t]=Pb[(s+t)*NC+j];
      #pragma unroll
      for(int t=0;t<8;t++){ Pb[(s+t)*NC+j]=run; run+=v[t]; }
    }
  }
}

template<int SEGS>
__global__ void scan_excl_t(float* __restrict__ P){
  int j = blockIdx.x*blockDim.x + threadIdx.x;
  float run=0.f;
  int s=0;
  for(; s+8<=SEGS; s+=8){
    float v[8];
    #pragma unroll
    for(int t=0;t<8;t++) v[t]=P[(s+t)*NC+j];
    #pragma unroll
    for(int t=0;t<8;t++){ P[(s+t)*NC+j]=run; run+=v[t]; }
  }
  for(; s<SEGS; s++){ float t=P[s*NC+j]; P[s*NC+j]=run; run+=t; }
}

__global__ void decay_finalize(const float* __restrict__ TD,
                               const float* __restrict__ Pd, float* __restrict__ dc){
  int s=blockIdx.x;
  size_t col = ((size_t)blockIdx.y*blockDim.x + threadIdx.x)*4;
  int i0=s*H3D, i1=min(M3,i0+H3D);
  float run[4];
  { F4u p; p.v=*(const float4*)(Pd+(size_t)s*NC+col);
    run[0]=p.f[0];run[1]=p.f[1];run[2]=p.f[2];run[3]=p.f[3]; }
  int i=i0;
  for(; i+8<=i1; i+=8){
    F4u tv[8];
    #pragma unroll
    for(int t=0;t<8;t++) tv[t].v=*(const float4*)(TD+(size_t)(i+t)*NC+col);
    #pragma unroll
    for(int t=0;t<8;t++){
      F4u o;
      #pragma unroll
      for(int k=0;k<4;k++){ run[k]+=tv[t].f[k]; o.f[k]=run[k]; }
      *(float4*)(dc+(size_t)(i+t)*NC+col)=o.v;
    }
  }
  for(; i<i1; i++){
    F4u tv,o; tv.v=*(const float4*)(TD+(size_t)i*NC+col);
    #pragma unroll
    for(int k=0;k<4;k++){ run[k]+=tv.f[k]; o.f[k]=run[k]; }
    *(float4*)(dc+(size_t)i*NC+col)=o.v;
  }
}

// ---- phase 1: b cumsum + decay upsample + b_adpt + x (float4 columns) ----
__global__ void phase1(const float* __restrict__ TB,
                       const float* __restrict__ Pb, const float* __restrict__ dc,
                       const float* __restrict__ fg, const float* __restrict__ fm,
                       const float* __restrict__ bold, const float* __restrict__ hX,
                       const float* __restrict__ recon,
                       float* __restrict__ out0, float* __restrict__ out3,
                       float* __restrict__ X){
  int s=blockIdx.x;
  size_t col = ((size_t)blockIdx.y*blockDim.x + threadIdx.x)*4;
  int i0=s*HSEG;
  float run[4];
  { F4u p; p.v=*(const float4*)(Pb+(size_t)s*NC+col);
    run[0]=p.f[0];run[1]=p.f[1];run[2]=p.f[2];run[3]=p.f[3]; }
  for(int g=0; g<HSEG; g+=4){
    F4u tb[4], fgv[4], fmv[4], bo[4], hx[4], rc[4], d0[4], d1[4];
    float fw[4];
    #pragma unroll
    for(int t=0;t<4;t++){
      int i=i0+g+t;
      size_t o=(size_t)i*NC+col;
      tb[t].v =*(const float4*)(TB+o);
      fgv[t].v=*(const float4*)(fg+o);
      fmv[t].v=*(const float4*)(fm+o);
      bo[t].v =*(const float4*)(bold+o);
      hx[t].v =*(const float4*)(hX+(size_t)(4*i)*NC+col);
      rc[t].v =*(const float4*)(recon+o);
      // jax.image.resize 'linear', half-pixel centers, edge clamp
      float c=(i+0.5f)*(683.0f/2048.0f)-0.5f;
      float fl=floorf(c); fw[t]=c-fl;
      int a0=(int)fl, a1=a0+1;
      a0=a0<0?0:(a0>M3-1?M3-1:a0);
      a1=a1<0?0:(a1>M3-1?M3-1:a1);
      d0[t].v=*(const float4*)(dc+(size_t)a0*NC+col);
      d1[t].v=*(const float4*)(dc+(size_t)a1*NC+col);
    }
    #pragma unroll
    for(int t=0;t<4;t++){
      int i=i0+g+t;
      size_t o=(size_t)i*NC+col;
      F4u o3v,o0v,xv;
      #pragma unroll
      for(int k=0;k<4;k++){
        run[k]+=tb[t].f[k];
        float d=(1.f-fw[t])*d0[t].f[k]+fw[t]*d1[t].f[k];
        float bf=run[k]+d*(1.f-fgv[t].f[k]);
        o3v.f[k]=bf;
        float ba=bf*fmv[t].f[k]+bo[t].f[k]*(1.f-fmv[t].f[k]);
        o0v.f[k]=ba;
        xv.f[k]=hx[t].f[k]+ba-rc[t].f[k];
      }
      *(float4*)(out3+o)=o3v.v;
      *(float4*)(out0+o)=o0v.v;
      *(float4*)(X+o)=xv.v;
    }
  }
}

// ---- horizontal 98-window sums via in-LDS row prefix (replicate-pad aware) ----
// wave-shfl scan (2 barriers) + skewed LDS + float4 windowed stores.

__global__ __launch_bounds__(256) void hbox_sq(const float* __restrict__ X,
                         float* __restrict__ H1, float* __restrict__ H2){
  __shared__ float C1[SK(NC)+1];
  __shared__ float C2[SK(NC)+1];
  __shared__ float w1[4];
  __shared__ float w2[4];
  int row=blockIdx.x, tid=threadIdx.x;
  int lane = tid & 63, wvid = tid >> 6;
  const float* xr = X + (size_t)row*NC;
  float v1[16], v2[16];
  int base=tid*16;
  float run1=0.f,run2=0.f;
  const float4* p4 = reinterpret_cast<const float4*>(xr+base);
  #pragma unroll
  for(int q=0;q<4;q++){
    float4 fq=p4[q];
    float e[4]={fq.x,fq.y,fq.z,fq.w};
    #pragma unroll
    for(int t=0;t<4;t++){
      run1+=e[t];      v1[q*4+t]=run1;
      run2+=e[t]*e[t]; v2[q*4+t]=run2;
    }
  }
  // wave-level inclusive scan of per-thread totals
  float s1=run1, s2=run2;
  #pragma unroll
  for(int off=1;off<64;off<<=1){
    float o1=__shfl_up(s1,off);
    float o2=__shfl_up(s2,off);
    if(lane>=off){ s1+=o1; s2+=o2; }
  }
  if(lane==63){ w1[wvid]=s1; w2[wvid]=s2; }
  __syncthreads();
  float b1=0.f,b2=0.f;
  #pragma unroll
  for(int q=0;q<4;q++) if(q<wvid){ b1+=w1[q]; b2+=w2[q]; }
  float ex1 = b1 + s1 - run1, ex2 = b2 + s2 - run2;
  if(tid==0){C1[SK(0)]=0.f;C2[SK(0)]=0.f;}
  #pragma unroll
  for(int e=0;e<16;e++){ int k=base+1+e; C1[SK(k)]=ex1+v1[e]; C2[SK(k)]=ex2+v2[e]; }
  __syncthreads();
  float first1=C1[SK(1)],  last1=C1[SK(NC)]-C1[SK(NC-1)];
  float first2=C2[SK(1)],  last2=C2[SK(NC)]-C2[SK(NC-1)];
  float* h1 = H1+(size_t)row*NC;
  float* h2 = H2+(size_t)row*NC;
  F4u s1o[4], s2o[4];
  #pragma unroll
  for(int e=0;e<16;e++){
    int j=base+e;
    int lo=j-48, hi=j+49;
    int li = lo<0?0:lo;
    int hc = hi>NC-1?NC-1:hi;
    float s1w=C1[SK(hc+1)]-C1[SK(li)];
    float s2w=C2[SK(hc+1)]-C2[SK(li)];
    if(lo<0){ s1w+=(float)(-lo)*first1; s2w+=(float)(-lo)*first2; }
    if(hi>NC-1){ s1w+=(float)(hi-(NC-1))*last1; s2w+=(float)(hi-(NC-1))*last2; }
    s1o[e>>2].f[e&3]=s1w; s2o[e>>2].f[e&3]=s2w;
  }
  #pragma unroll
  for(int q=0;q<4;q++){
    *(float4*)(h1+base+4*q)=s1o[q].v;
    *(float4*)(h2+base+4*q)=s2o[q].v;
  }
}

__global__ __launch_bounds__(256) void hbox_two(const float* __restrict__ A,
                         const float* __restrict__ B,
                         float* __restrict__ H1, float* __restrict__ H2){
  __shared__ float C1[SK(NC)+1];
  __shared__ float C2[SK(NC)+1];
  __shared__ float w1[4];
  __shared__ float w2[4];
  int row=blockIdx.x, tid=threadIdx.x;
  int lane = tid & 63, wvid = tid >> 6;
  const float* ar = A + (size_t)row*NC;
  const float* br = B + (size_t)row*NC;
  float v1[16], v2[16];
  int base=tid*16;
  float run1=0.f,run2=0.f;
  const float4* pa = reinterpret_cast<const float4*>(ar+base);
  const float4* pb = reinterpret_cast<const float4*>(br+base);
  #pragma unroll
  for(int q=0;q<4;q++){
    float4 fa=pa[q]; float4 fb=pb[q];
    float ea[4]={fa.x,fa.y,fa.z,fa.w};
    float eb[4]={fb.x,fb.y,fb.z,fb.w};
    #pragma unroll
    for(int t=0;t<4;t++){
      run1+=ea[t]; v1[q*4+t]=run1;
      run2+=eb[t]; v2[q*4+t]=run2;
    }
  }
  float s1=run1, s2=run2;
  #pragma unroll
  for(int off=1;off<64;off<<=1){
    float o1=__shfl_up(s1,off);
    float o2=__shfl_up(s2,off);
    if(lane>=off){ s1+=o1; s2+=o2; }
  }
  if(lane==63){ w1[wvid]=s1; w2[wvid]=s2; }
  __syncthreads();
  float b1=0.f,b2=0.f;
  #pragma unroll
  for(int q=0;q<4;q++) if(q<wvid){ b1+=w1[q]; b2+=w2[q]; }
  float ex1 = b1 + s1 - run1, ex2 = b2 + s2 - run2;
  if(tid==0){C1[SK(0)]=0.f;C2[SK(0)]=0.f;}
  #pragma unroll
  for(int e=0;e<16;e++){ int k=base+1+e; C1[SK(k)]=ex1+v1[e]; C2[SK(k)]=ex2+v2[e]; }
  __syncthreads();
  float first1=C1[SK(1)], last1=C1[SK(NC)]-C1[SK(NC-1)];
  float first2=C2[SK(1)], last2=C2[SK(NC)]-C2[SK(NC-1)];
  float* h1 = H1+(size_t)row*NC;
  float* h2 = H2+(size_t)row*NC;
  F4u s1o[4], s2o[4];
  #pragma unroll
  for(int e=0;e<16;e++){
    int j=base+e;
    int lo=j-48, hi=j+49;
    int li = lo<0?0:lo;
    int hc = hi>NC-1?NC-1:hi;
    float s1w=C1[SK(hc+1)]-C1[SK(li)];
    float s2w=C2[SK(hc+1)]-C2[SK(li)];
    if(lo<0){ s1w+=(float)(-lo)*first1; s2w+=(float)(-lo)*first2; }
    if(hi>NC-1){ s1w+=(float)(hi-(NC-1))*last1; s2w+=(float)(hi-(NC-1))*last2; }
    s1o[e>>2].f[e&3]=s1w; s2o[e>>2].f[e&3]=s2w;
  }
  #pragma unroll
  for(int q=0;q<4;q++){
    *(float4*)(h1+base+4*q)=s1o[q].v;
    *(float4*)(h2+base+4*q)=s2o[q].v;
  }
}

// ---- vertical 98-window sliding sums (rows i-48..i+49 clamped), float2 ----

__global__ void vbox_stage1(const float* __restrict__ H1, const float* __restrict__ H2,
                            float* __restrict__ Aimg, float* __restrict__ BBimg){
  int tile = blockIdx.x;
  size_t col = ((size_t)blockIdx.y*blockDim.x + threadIdx.x)*2;
  int i0 = tile*VT;
  int ip = i0-1;                 // init window at row i0-1, slide into each row
  float Sa[2]={0.f,0.f}, Sb[2]={0.f,0.f};
  for(int g=0; g<98; g+=14){
    F2u a1[14], a2[14];
    #pragma unroll
    for(int t=0;t<14;t++){
      int c = ip-48+g+t;
      int cc = c<0?0:(c>MR-1?MR-1:c);
      a1[t].v=*(const float2*)(H1+(size_t)cc*NC+col);
      a2[t].v=*(const float2*)(H2+(size_t)cc*NC+col);
    }
    #pragma unroll
    for(int t=0;t<14;t++){
      #pragma unroll
      for(int k=0;k<2;k++){ Sa[k]+=a1[t].f[k]; Sb[k]+=a2[t].f[k]; }
    }
  }
  for(int g=0; g<VT; g+=8){
    F2u hu1[8],hd1[8],hu2[8],hd2[8];
    #pragma unroll
    for(int t=0;t<8;t++){
      int i=i0+g+t;
      int up=i+49; up=up>MR-1?MR-1:up;
      int dn=i-49; dn=dn<0?0:dn;
      hu1[t].v=*(const float2*)(H1+(size_t)up*NC+col);
      hd1[t].v=*(const float2*)(H1+(size_t)dn*NC+col);
      hu2[t].v=*(const float2*)(H2+(size_t)up*NC+col);
      hd2[t].v=*(const float2*)(H2+(size_t)dn*NC+col);
    }
    #pragma unroll
    for(int t=0;t<8;t++){
      int i=i0+g+t;
      F2u Av, Bv;
      #pragma unroll
      for(int k=0;k<2;k++){
        Sa[k] += hu1[t].f[k]-hd1[t].f[k];
        Sb[k] += hu2[t].f[k]-hd2[t].f[k];
        float mx = Sa[k]*NORM, mx2 = Sb[k]*NORM;
        float var = mx2 - mx*mx;
        float A = var/(var+1.0f);
        Av.f[k]=A; Bv.f[k]=mx - A*mx;
      }
      *(float2*)(Aimg+(size_t)i*NC+col)=Av.v;
      *(float2*)(BBimg+(size_t)i*NC+col)=Bv.v;
    }
  }
}

// ---- vbox stage2 fused with phase3's diff/clip/scale partial-sum ----
// S lands in out2 (diff_adpt slot) whose previous content (bb_img) is dead.
// Partials at 32-row granularity (PSEG=64 segments) so phase3_final keeps a
// 256-block float4 grid. Tile-0: dpre=+3e38 forces S[row0]=0 via the clip.

__global__ void vbox2_fused(const float* __restrict__ H1, const float* __restrict__ H2,
                            const float* __restrict__ X, const float* __restrict__ ww,
                            float* __restrict__ diff, float* __restrict__ S,
                            float* __restrict__ Pc){
  int tile = blockIdx.x;
  size_t col = ((size_t)blockIdx.y*blockDim.x + threadIdx.x)*2;
  int i0 = tile*VT;
  int ip = i0-1;
  float Sa[2]={0.f,0.f}, Sb[2]={0.f,0.f};
  for(int g=0; g<98; g+=14){
    F2u a1[14], a2[14];
    #pragma unroll
    for(int t=0;t<14;t++){
      int c = ip-48+g+t;
      int cc = c<0?0:(c>MR-1?MR-1:c);
      a1[t].v=*(const float2*)(H1+(size_t)cc*NC+col);
      a2[t].v=*(const float2*)(H2+(size_t)cc*NC+col);
    }
    #pragma unroll
    for(int t=0;t<14;t++){
      #pragma unroll
      for(int k=0;k<2;k++){ Sa[k]+=a1[t].f[k]; Sb[k]+=a2[t].f[k]; }
    }
  }
  float dpre[2], accA[2]={0.f,0.f}, accB[2]={0.f,0.f};
  if(tile==0){ dpre[0]=3.0e38f; dpre[1]=3.0e38f; }
  else {
    F2u xp; xp.v=*(const float2*)(X+(size_t)ip*NC+col);
    #pragma unroll
    for(int k=0;k<2;k++) dpre[k]=(Sa[k]*NORM)*xp.f[k]+Sb[k]*NORM;
  }
  for(int g=0; g<VT; g+=8){
    F2u hu1[8],hd1[8],hu2[8],hd2[8],xv[8],wv[8];
    #pragma unroll
    for(int t=0;t<8;t++){
      int i=i0+g+t;
      int up=i+49; up=up>MR-1?MR-1:up;
      int dn=i-49; dn=dn<0?0:dn;
      hu1[t].v=*(const float2*)(H1+(size_t)up*NC+col);
      hd1[t].v=*(const float2*)(H1+(size_t)dn*NC+col);
      hu2[t].v=*(const float2*)(H2+(size_t)up*NC+col);
      hd2[t].v=*(const float2*)(H2+(size_t)dn*NC+col);
      xv[t].v =*(const float2*)(X+(size_t)i*NC+col);
      wv[t].v =*(const float2*)(ww+(size_t)i*NC+col);
    }
    float* acc = (g<VT/2)? accA : accB;
    #pragma unroll
    for(int t=0;t<8;t++){
      int i=i0+g+t;
      F2u dv, sv;
      #pragma unroll
      for(int k=0;k<2;k++){
        Sa[k] += hu1[t].f[k]-hd1[t].f[k];
        Sb[k] += hu2[t].f[k]-hd2[t].f[k];
        float d = (Sa[k]*NORM)*xv[t].f[k] + Sb[k]*NORM;
        dv.f[k]=d;
        float v = d-dpre[k]; v = v>0.f? v:0.f;
        float s = v*sp(wv[t].f[k]);
        sv.f[k]=s; acc[k]+=s; dpre[k]=d;
      }
      *(float2*)(diff+(size_t)i*NC+col)=dv.v;
      *(float2*)(S+(size_t)i*NC+col)=sv.v;
    }
  }
  F2u pa, pb2;
  pa.f[0]=accA[0]; pa.f[1]=accA[1];
  pb2.f[0]=accB[0]; pb2.f[1]=accB[1];
  *(float2*)(Pc+(size_t)(2*tile)*NC+col)=pa.v;
  *(float2*)(Pc+(size_t)(2*tile+1)*NC+col)=pb2.v;
}

// ---- phase 3 final: column cumsum of S (in out2, overwritten in place),
//      write diff_adpt, update b_adpt. 32-row segments, float4 columns ----

__global__ void phase3_final(const float* __restrict__ Pc,
                             float* __restrict__ out0, float* __restrict__ out2){
  int s=blockIdx.x;
  size_t col = ((size_t)blockIdx.y*blockDim.x + threadIdx.x)*4;
  int i0=s*(MR/PSEG);
  float run[4];
  { F4u p; p.v=*(const float4*)(Pc+(size_t)s*NC+col);
    run[0]=p.f[0];run[1]=p.f[1];run[2]=p.f[2];run[3]=p.f[3]; }
  for(int g=0; g<MR/PSEG; g+=8){
    F4u sv[8], o0[8];
    #pragma unroll
    for(int t=0;t<8;t++){ size_t o=(size_t)(i0+g+t)*NC+col;
      sv[t].v=*(const float4*)(out2+o); o0[t].v=*(const float4*)(out0+o); }
    #pragma unroll
    for(int t=0;t<8;t++){
      size_t o=(size_t)(i0+g+t)*NC+col;
      F4u c2, c0;
      #pragma unroll
      for(int k=0;k<4;k++){
        run[k]+=sv[t].f[k];
        c2.f[k]=run[k];
        c0.f[k]=o0[t].f[k]-run[k];
      }
      *(float4*)(out2+o)=c2.v;
      *(float4*)(out0+o)=c0.v;
    }
  }
}

extern "C" void kernel_launch(void* const* d_in, const int* in_sizes, int n_in,
                              void* d_out, int out_size, void* d_ws, size_t ws_size,
                              hipStream_t stream){
  const float* b    = (const float*)d_in[0];
  const float* bneg = (const float*)d_in[1];
  const float* fg   = (const float*)d_in[2];
  const float* hX   = (const float*)d_in[3];
  const float* recon= (const float*)d_in[4];
  const float* fm   = (const float*)d_in[5];
  const float* bold = (const float*)d_in[6];
  // d_in[7] = r (int scalar, ==4) — shapes hardcoded
  const float* w    = (const float*)d_in[8];
  const float* dcol = (const float*)d_in[9];
  const float* ww   = (const float*)d_in[10];

  float* out  = (float*)d_out;
  float* out0 = out;                       // b_adpt
  float* out1 = out + (size_t)MR*NC;       // diff (A_img scratch mid-pipe)
  float* out2 = out + 2ull*MR*NC;          // diff_adpt (bb_img scratch, then S, then cumsum)
  float* out3 = out + 3ull*MR*NC;          // b

  float* wsf = (float*)d_ws;
  float* X  = wsf;                         // MR*NC
  float* H1 = wsf + 1ull*MR*NC;            // MR*NC   (TD early)
  float* H2 = wsf + 2ull*MR*NC;            // MR*NC   (TB early)
  float* DC = wsf + 3ull*MR*NC;            // M3*NC
  float* Pb = DC + (size_t)M3*NC;          // SEG*NC
  float* Pd = Pb + (size_t)SEG*NC;         // SEGD*NC
  float* Pc = Pd + (size_t)SEGD*NC;        // PSEG*NC
  float* TD = H1;                          // M3*NC  (dead before hbox_sq writes H1)
  float* TB = H2;                          // MR*NC  (dead before hbox_sq writes H2)

  seg_sum_both <<<dim3(SEGD+SEG,NC/1024),256,0,stream>>>(bneg,dcol,b,w,TD,Pd,TB,Pb);
  scan_excl_both<<<NC/256,256,0,stream>>>(Pd,Pb);
  decay_finalize<<<dim3(SEGD,NC/1024),256,0,stream>>>(TD,Pd,DC);
  phase1       <<<dim3(SEG, NC/1024),256,0,stream>>>(TB,Pb,DC,fg,fm,bold,hX,recon,out0,out3,X);
  hbox_sq      <<<MR,256,0,stream>>>(X,H1,H2);
  vbox_stage1  <<<dim3(VTILES,NC/512),256,0,stream>>>(H1,H2,out1,out2);
  hbox_two     <<<MR,256,0,stream>>>(out1,out2,H1,H2);
  vbox2_fused  <<<dim3(VTILES,NC/512),256,0,stream>>>(H1,H2,X,ww,out1,out2,Pc);
  scan_excl_t<PSEG><<<NC/256,256,0,stream>>>(Pc);
  phase3_final <<<dim3(PSEG,NC/1024),256,0,stream>>>(Pc,out0,out2);
}